// Round 1
// baseline (689.453 us; speedup 1.0000x reference)
//
#include <hip/hip_runtime.h>

#define BB 16
#define KK 2048
#define NPROPN 256
#define NS 16
#define CSEED 256
#define CMLP 128
#define CIN 259
#define NHH 12
#define NSCC 18
#define NCLSS 18
#define OUTCH 119
#define KZZ 1024

// output offsets in floats (concatenated tuple order)
#define O0  0UL        // objectness (B,256,2)
#define O1  8192UL     // center (B,256,3)
#define O2  20480UL    // heading_scores (B,256,12)
#define O3  69632UL    // heading_res (B,256,12)
#define O4  118784UL   // size_scores (B,256,18)
#define O5  192512UL   // size_res (B,256,18,3)
#define O6  413696UL   // sem_cls (B,256,18)
#define O7  487424UL   // surface_center_pred (B,2048,3)
#define O8  585728UL   // surface_center_feature_pred (B,128,2048)
#define O9  4780032UL  // line_center (B,1024,3)
#define O10 4829184UL  // obj_surface_center (B,1536,3)
#define O11 4902912UL  // obj_surface_feature (B,128,1536)

__global__ __launch_bounds__(256) void fps_kernel(const float* __restrict__ xyz,
                                                  float* __restrict__ new_xyz) {
  const int b = blockIdx.x;
  const int t = threadIdx.x;
  __shared__ float sx[KK], sy[KK], sz[KK], sd[KK];
  __shared__ float wv[4];
  __shared__ int wi[4];
  __shared__ int scur;
  const float* p = xyz + (size_t)b * KK * 3;
  for (int i = t; i < KK; i += 256) {
    sx[i] = p[i * 3 + 0];
    sy[i] = p[i * 3 + 1];
    sz[i] = p[i * 3 + 2];
    sd[i] = 1e10f;
  }
  __syncthreads();
  int cur = 0;
  const int lane = t & 63, w = t >> 6;
  for (int it = 0; it < NPROPN; ++it) {
    float cx = sx[cur], cy = sy[cur], cz = sz[cur];
    if (t == 0) {
      float* o = new_xyz + ((size_t)b * NPROPN + it) * 3;
      o[0] = cx; o[1] = cy; o[2] = cz;
    }
    float bv = -1.0f;
    int bi = 0;
    const int base = t * 8;
#pragma unroll
    for (int j = 0; j < 8; ++j) {
      int i = base + j;
      // exact IEEE f32, no contraction: matches numpy ((dx^2+dy^2)+dz^2)
      float dx = __fsub_rn(sx[i], cx);
      float dy = __fsub_rn(sy[i], cy);
      float dz = __fsub_rn(sz[i], cz);
      float d = __fadd_rn(__fadd_rn(__fmul_rn(dx, dx), __fmul_rn(dy, dy)), __fmul_rn(dz, dz));
      float nd = fminf(sd[i], d);
      sd[i] = nd;
      if (nd > bv) { bv = nd; bi = i; }  // strict > : first-index tie-break (ascending i)
    }
#pragma unroll
    for (int off = 32; off; off >>= 1) {
      float v2 = __shfl_down(bv, off);
      int i2 = __shfl_down(bi, off);
      if (v2 > bv || (v2 == bv && i2 < bi)) { bv = v2; bi = i2; }
    }
    if (lane == 0) { wv[w] = bv; wi[w] = bi; }
    __syncthreads();
    if (t == 0) {
      float v = wv[0]; int i = wi[0];
      for (int q = 1; q < 4; ++q)
        if (wv[q] > v || (wv[q] == v && wi[q] < i)) { v = wv[q]; i = wi[q]; }
      scur = i;
    }
    __syncthreads();
    cur = scur;
  }
}

__global__ __launch_bounds__(256) void proposal_kernel(
    const float* __restrict__ vote_xyz, const float* __restrict__ vote_feat,
    const float* __restrict__ new_xyz, const float* __restrict__ msa,
    const float* __restrict__ w0, const float* __restrict__ s0, const float* __restrict__ b0,
    const float* __restrict__ w1, const float* __restrict__ s1, const float* __restrict__ b1,
    const float* __restrict__ w2, const float* __restrict__ s2, const float* __restrict__ b2,
    const float* __restrict__ c1w, const float* __restrict__ c1b,
    const float* __restrict__ bn1s, const float* __restrict__ bn1b,
    const float* __restrict__ c2w, const float* __restrict__ c2b,
    const float* __restrict__ bn2s, const float* __restrict__ bn2b,
    const float* __restrict__ c3w, const float* __restrict__ c3b,
    float* __restrict__ out) {
  const int bid = blockIdx.x;
  const int b = bid >> 8, pp = bid & 255;
  const int t = threadIdx.x;

  __shared__ float g[NS][CIN + 1];     // 16 x 260
  __shared__ float hA[NS][CMLP + 4];   // 16 x 132
  __shared__ float hB[NS][CMLP + 4];
  __shared__ int cnt[256];
  __shared__ int sel[NS];
  __shared__ int stotal;
  __shared__ float feat[CMLP];
  __shared__ float n1[CMLP], n2[CMLP], ntv[OUTCH + 1];
  __shared__ float scenter[3], shalf[3];
  __shared__ int scls;

  const float* nx = new_xyz + ((size_t)b * NPROPN + pp) * 3;
  const float cx = nx[0], cy = nx[1], cz = nx[2];
  const float* px = vote_xyz + (size_t)b * KK * 3;
  const float RR = 0.09000000357627869f;  // f32(0.3*0.3)

  // ---- ball query: first <=16 in-radius indices in ascending order ----
  unsigned mask = 0;
  {
    const int base = t * 8;
#pragma unroll
    for (int j = 0; j < 8; ++j) {
      int i = base + j;
      float dx = __fsub_rn(px[i * 3 + 0], cx);
      float dy = __fsub_rn(px[i * 3 + 1], cy);
      float dz = __fsub_rn(px[i * 3 + 2], cz);
      float d = __fadd_rn(__fadd_rn(__fmul_rn(dx, dx), __fmul_rn(dy, dy)), __fmul_rn(dz, dz));
      if (d <= RR) mask |= (1u << j);
    }
  }
  cnt[t] = __popc(mask);
  __syncthreads();
  if (t == 0) {
    int run = 0;
    for (int i = 0; i < 256; ++i) { int tmp = cnt[i]; cnt[i] = run; run += tmp; }
    stotal = run;
  }
  __syncthreads();
  {
    int pos = cnt[t];
    const int base = t * 8;
    for (int j = 0; j < 8; ++j) {
      if (mask & (1u << j)) {
        if (pos < NS) sel[pos] = base + j;
        ++pos;
      }
    }
  }
  __syncthreads();
  if (t == 0) {
    int tot = stotal;
    int first = (tot > 0) ? sel[0] : 0;
    for (int i = tot; i < NS; ++i) sel[i] = first;
  }
  __syncthreads();

  // ---- gather g rows: [gx(3) | features(256)] ----
  {
    const int s = t >> 4, j = t & 15;
    const int idx = sel[s];
    const float* fb = vote_feat + (size_t)b * CSEED * KK + idx;
    for (int cc = j; cc < CIN; cc += 16) {
      float v;
      if (cc < 3) {
        float pv = px[idx * 3 + cc];
        float cv = (cc == 0) ? cx : ((cc == 1) ? cy : cz);
        v = __fdiv_rn(__fsub_rn(pv, cv), 0.3f);
      } else {
        v = fb[(size_t)(cc - 3) * KK];
      }
      g[s][cc] = v;
    }
  }
  __syncthreads();

  // ---- MLP layer 0: 259 -> 128 ----
  {
    const int o = t & 127, sg = t >> 7, sb = sg * 8;
    float acc[8] = {0, 0, 0, 0, 0, 0, 0, 0};
    const float* wr = w0 + (size_t)o * CIN;
    for (int k = 0; k < CIN; ++k) {
      float w = wr[k];
#pragma unroll
      for (int i = 0; i < 8; ++i) acc[i] = fmaf(w, g[sb + i][k], acc[i]);
    }
    float sc = s0[o], bi = b0[o];
#pragma unroll
    for (int i = 0; i < 8; ++i) {
      float v = fmaf(acc[i], sc, bi);
      hA[sb + i][o] = v > 0.f ? v : 0.f;
    }
  }
  __syncthreads();
  // ---- MLP layer 1: 128 -> 128 ----
  {
    const int o = t & 127, sg = t >> 7, sb = sg * 8;
    float acc[8] = {0, 0, 0, 0, 0, 0, 0, 0};
    const float* wr = w1 + (size_t)o * CMLP;
    for (int k = 0; k < CMLP; ++k) {
      float w = wr[k];
#pragma unroll
      for (int i = 0; i < 8; ++i) acc[i] = fmaf(w, hA[sb + i][k], acc[i]);
    }
    float sc = s1[o], bi = b1[o];
#pragma unroll
    for (int i = 0; i < 8; ++i) {
      float v = fmaf(acc[i], sc, bi);
      hB[sb + i][o] = v > 0.f ? v : 0.f;
    }
  }
  __syncthreads();
  // ---- MLP layer 2: 128 -> 128 ----
  {
    const int o = t & 127, sg = t >> 7, sb = sg * 8;
    float acc[8] = {0, 0, 0, 0, 0, 0, 0, 0};
    const float* wr = w2 + (size_t)o * CMLP;
    for (int k = 0; k < CMLP; ++k) {
      float w = wr[k];
#pragma unroll
      for (int i = 0; i < 8; ++i) acc[i] = fmaf(w, hB[sb + i][k], acc[i]);
    }
    float sc = s2[o], bi = b2[o];
#pragma unroll
    for (int i = 0; i < 8; ++i) {
      float v = fmaf(acc[i], sc, bi);
      hA[sb + i][o] = v > 0.f ? v : 0.f;
    }
  }
  __syncthreads();

  // ---- maxpool over samples + obj_surface_feature tile x6 ----
  if (t < CMLP) {
    float m = hA[0][t];
#pragma unroll
    for (int s = 1; s < NS; ++s) m = fmaxf(m, hA[s][t]);
    feat[t] = m;
    float* o11 = out + O11 + (size_t)b * CMLP * 1536 + (size_t)t * 1536 + pp;
#pragma unroll
    for (int r = 0; r < 6; ++r) o11[r * 256] = m;
  }
  __syncthreads();

  // ---- conv1 + bn1 + relu ----
  if (t < CMLP) {
    float acc = 0.f;
    const float* wr = c1w + (size_t)t * CMLP;
    for (int k = 0; k < CMLP; ++k) acc = fmaf(wr[k], feat[k], acc);
    float v = acc + c1b[t];
    v = fmaf(v, bn1s[t], bn1b[t]);
    n1[t] = v > 0.f ? v : 0.f;
  }
  __syncthreads();
  // ---- conv2 + bn2 + relu ----
  if (t < CMLP) {
    float acc = 0.f;
    const float* wr = c2w + (size_t)t * CMLP;
    for (int k = 0; k < CMLP; ++k) acc = fmaf(wr[k], n1[k], acc);
    float v = acc + c2b[t];
    v = fmaf(v, bn2s[t], bn2b[t]);
    n2[t] = v > 0.f ? v : 0.f;
  }
  __syncthreads();
  // ---- conv3 (119 outputs) ----
  if (t < OUTCH) {
    float acc = 0.f;
    const float* wr = c3w + (size_t)t * CMLP;
    for (int k = 0; k < CMLP; ++k) acc = fmaf(wr[k], n2[k], acc);
    ntv[t] = acc + c3b[t];
  }
  __syncthreads();

  // ---- heads ----
  const size_t bp = (size_t)b * NPROPN + pp;
  if (t < 2) out[O0 + bp * 2 + t] = ntv[t];
  if (t < 3) {
    float cv = ((t == 0) ? cx : ((t == 1) ? cy : cz)) + ntv[2 + t];
    scenter[t] = cv;
    out[O1 + bp * 3 + t] = cv;
  }
  if (t < NHH) out[O2 + bp * NHH + t] = ntv[5 + t];
  if (t < NHH) out[O3 + bp * NHH + t] = ntv[5 + NHH + t] * (float)(3.14159265358979323846 / 12.0);
  if (t < NSCC) out[O4 + bp * NSCC + t] = ntv[29 + t];
  if (t < 54) out[O5 + bp * 54 + t] = ntv[47 + t] * msa[t];
  if (t < NCLSS) out[O6 + bp * NCLSS + t] = ntv[101 + t];
  if (t == 0) {
    float bvv = ntv[29];
    int bii = 0;
    for (int i2 = 1; i2 < NSCC; ++i2)
      if (ntv[29 + i2] > bvv) { bvv = ntv[29 + i2]; bii = i2; }  // strict >: first max
    scls = bii;
  }
  __syncthreads();
  if (t < 3) {
    float m = msa[scls * 3 + t];
    shalf[t] = (m + ntv[47 + scls * 3 + t] * m) * 0.5f;
  }
  __syncthreads();
  if (t < 18) {
    const int r = t / 3, j2 = t % 3;
    const int axis[6] = {2, 2, 1, 1, 0, 0};
    float v = scenter[j2];
    if (j2 == axis[r]) v = (r & 1) ? (v - shalf[j2]) : (v + shalf[j2]);
    out[O10 + (size_t)b * 1536 * 3 + (size_t)(r * 256 + pp) * 3 + j2] = v;
  }
}

__global__ __launch_bounds__(256) void surf_kernel(
    const float* __restrict__ pz, const float* __restrict__ cz,
    const float* __restrict__ pxy, const float* __restrict__ cxy,
    const float* __restrict__ pl, const float* __restrict__ cl,
    float* __restrict__ out) {
  int i = blockIdx.x * 256 + threadIdx.x;
  if (i >= 3 * BB * KZZ) return;
  int src = i / (BB * KZZ);
  int rem = i % (BB * KZZ);
  int b = rem / KZZ, k = rem % KZZ;
  const float* ps = (src == 0) ? pz : ((src == 1) ? pxy : pl);
  const float* pc = (src == 0) ? cz : ((src == 1) ? cxy : cl);
  float x0 = ps[((size_t)b * 2 + 0) * KZZ + k];
  float x1 = ps[((size_t)b * 2 + 1) * KZZ + k];
  // softmax(x)[1] <= 0.5  <=>  x1 <= x0
  float add = (x1 <= x0) ? 10.0f : 0.0f;
  size_t dst;
  if (src == 0) dst = O7 + ((size_t)b * 2048 + k) * 3;
  else if (src == 1) dst = O7 + ((size_t)b * 2048 + 1024 + k) * 3;
  else dst = O9 + ((size_t)b * KZZ + k) * 3;
  const float* c3 = pc + ((size_t)b * KZZ + k) * 3;
  out[dst + 0] = c3[0] + add;
  out[dst + 1] = c3[1] + add;
  out[dst + 2] = c3[2] + add;
}

__global__ __launch_bounds__(256) void featcopy_kernel(
    const float* __restrict__ az, const float* __restrict__ axy,
    float* __restrict__ out) {
  int i = blockIdx.x * 256 + threadIdx.x;  // one float4 each; total 1048576
  int q = i & 511;
  int bc = i >> 9;  // (b*128 + c) in [0, 2048)
  int half = q >> 8, k4 = q & 255;
  const float4* src = (const float4*)((half == 0) ? az : axy);
  float4 v = src[(size_t)bc * 256 + k4];
  float4* dst = (float4*)(out + O8);
  dst[(size_t)bc * 512 + q] = v;
}

extern "C" void kernel_launch(void* const* d_in, const int* in_sizes, int n_in,
                              void* d_out, int out_size, void* d_ws, size_t ws_size,
                              hipStream_t stream) {
  (void)in_sizes; (void)n_in; (void)out_size; (void)ws_size;
  const float* vote_xyz = (const float*)d_in[0];
  const float* vote_feat = (const float*)d_in[1];
  const float* pz   = (const float*)d_in[2];
  const float* cz   = (const float*)d_in[3];
  const float* az   = (const float*)d_in[4];
  const float* pxy  = (const float*)d_in[5];
  const float* cxy  = (const float*)d_in[6];
  const float* axy  = (const float*)d_in[7];
  const float* pl   = (const float*)d_in[8];
  const float* cl   = (const float*)d_in[9];
  // d_in[10] aggregated_feature_line: unused by reference outputs
  const float* msa  = (const float*)d_in[11];
  const float* w0   = (const float*)d_in[12];
  const float* s0   = (const float*)d_in[13];
  const float* b0   = (const float*)d_in[14];
  const float* w1   = (const float*)d_in[15];
  const float* s1   = (const float*)d_in[16];
  const float* b1   = (const float*)d_in[17];
  const float* w2   = (const float*)d_in[18];
  const float* s2   = (const float*)d_in[19];
  const float* b2   = (const float*)d_in[20];
  const float* c1w  = (const float*)d_in[21];
  const float* c1b  = (const float*)d_in[22];
  const float* bn1s = (const float*)d_in[23];
  const float* bn1b = (const float*)d_in[24];
  const float* c2w  = (const float*)d_in[25];
  const float* c2b  = (const float*)d_in[26];
  const float* bn2s = (const float*)d_in[27];
  const float* bn2b = (const float*)d_in[28];
  const float* c3w  = (const float*)d_in[29];
  const float* c3b  = (const float*)d_in[30];
  float* out = (float*)d_out;
  float* new_xyz = (float*)d_ws;  // B*256*3 floats = 48 KB

  hipLaunchKernelGGL(fps_kernel, dim3(BB), dim3(256), 0, stream, vote_xyz, new_xyz);
  hipLaunchKernelGGL(proposal_kernel, dim3(BB * NPROPN), dim3(256), 0, stream,
                     vote_xyz, vote_feat, new_xyz, msa,
                     w0, s0, b0, w1, s1, b1, w2, s2, b2,
                     c1w, c1b, bn1s, bn1b, c2w, c2b, bn2s, bn2b, c3w, c3b, out);
  hipLaunchKernelGGL(surf_kernel, dim3((3 * BB * KZZ + 255) / 256), dim3(256), 0, stream,
                     pz, cz, pxy, cxy, pl, cl, out);
  hipLaunchKernelGGL(featcopy_kernel, dim3((BB * CMLP * 512) / 256), dim3(256), 0, stream,
                     az, axy, out);
}

// Round 2
// 496.647 us; speedup vs baseline: 1.3882x; 1.3882x over previous
//
#include <hip/hip_runtime.h>

#define BB 16
#define KK 2048
#define NPROPN 256
#define NS 16
#define CSEED 256
#define CMLP 128
#define CIN 259
#define OUTCH 119
#define KZZ 1024

// output offsets in floats (concatenated tuple order)
#define O0  0UL
#define O1  8192UL
#define O2  20480UL
#define O3  69632UL
#define O4  118784UL
#define O5  192512UL
#define O6  413696UL
#define O7  487424UL
#define O8  585728UL
#define O9  4780032UL
#define O10 4829184UL
#define O11 4902912UL

// ws layout (floats)
#define WS_NEWXYZ 0
#define WS_W0T 12288
#define WS_W1T 45440
#define WS_W2T 61824
#define WS_C1T 78208
#define WS_C2T 94592
#define WS_C3T 110976

#define PREP_FPS_END 16
#define PREP_TR_END 466    // 450 blocks, 2 rows each, 899 rows
#define PREP_SURF_END 658  // 192 blocks
#define PREP_COPY_END 4754 // 4096 blocks

__device__ __forceinline__ void fma4(float4& a, float s, const float4& w) {
  a.x = fmaf(s, w.x, a.x); a.y = fmaf(s, w.y, a.y);
  a.z = fmaf(s, w.z, a.z); a.w = fmaf(s, w.w, a.w);
}
__device__ __forceinline__ float fget(const float4& v, int r) {
  return r == 0 ? v.x : (r == 1 ? v.y : (r == 2 ? v.z : v.w));
}

__global__ __launch_bounds__(256) void prep_kernel(
    const float* __restrict__ xyz,
    const float* __restrict__ w0, const float* __restrict__ w1, const float* __restrict__ w2,
    const float* __restrict__ c1w, const float* __restrict__ c2w, const float* __restrict__ c3w,
    const float* __restrict__ pz, const float* __restrict__ cz,
    const float* __restrict__ pxy, const float* __restrict__ cxy,
    const float* __restrict__ pl, const float* __restrict__ cl,
    const float* __restrict__ az, const float* __restrict__ axy,
    float* __restrict__ wsf, float* __restrict__ out) {
  const int bid = blockIdx.x;
  const int t = threadIdx.x;
  __shared__ float sx[KK], sy[KK], sz[KK];
  __shared__ float wvv[2][4];
  __shared__ int wii[2][4];

  if (bid < PREP_FPS_END) {
    // ---------------- FPS: one block per batch ----------------
    const int b = bid;
    const float* p = xyz + (size_t)b * KK * 3;
    float pxr[8], pyr[8], pzr[8], dd[8];
#pragma unroll
    for (int j = 0; j < 8; ++j) {
      int i = j * 256 + t;
      float x = p[i * 3 + 0], y = p[i * 3 + 1], z = p[i * 3 + 2];
      pxr[j] = x; pyr[j] = y; pzr[j] = z; dd[j] = 1e10f;
      sx[i] = x; sy[i] = y; sz[i] = z;
    }
    __syncthreads();
    int cur = 0;
    const int lane = t & 63, w = t >> 6;
    float* nxw = wsf + WS_NEWXYZ + (size_t)b * NPROPN * 3;
    for (int it = 0; it < NPROPN; ++it) {
      float cx = sx[cur], cy = sy[cur], cz2 = sz[cur];
      if (t == 0) { nxw[it * 3 + 0] = cx; nxw[it * 3 + 1] = cy; nxw[it * 3 + 2] = cz2; }
      float best = -1.0f; int bidx = 0;
#pragma unroll
      for (int j = 0; j < 8; ++j) {
        float dx = __fsub_rn(pxr[j], cx);
        float dy = __fsub_rn(pyr[j], cy);
        float dz = __fsub_rn(pzr[j], cz2);
        float d = __fadd_rn(__fadd_rn(__fmul_rn(dx, dx), __fmul_rn(dy, dy)), __fmul_rn(dz, dz));
        float nd = fminf(dd[j], d);
        dd[j] = nd;
        if (nd > best) { best = nd; bidx = j * 256 + t; }
      }
#pragma unroll
      for (int off = 32; off; off >>= 1) {
        float v2 = __shfl_down(best, off);
        int i2 = __shfl_down(bidx, off);
        if (v2 > best || (v2 == best && i2 < bidx)) { best = v2; bidx = i2; }
      }
      const int pb = it & 1;
      if (lane == 0) { wvv[pb][w] = best; wii[pb][w] = bidx; }
      __syncthreads();
      float v = wvv[pb][0]; int ci = wii[pb][0];
#pragma unroll
      for (int q = 1; q < 4; ++q) {
        float vq = wvv[pb][q]; int iq = wii[pb][q];
        if (vq > v || (vq == v && iq < ci)) { v = vq; ci = iq; }
      }
      cur = ci;
    }
    return;
  }

  if (bid < PREP_TR_END) {
    // ---------------- weight transpose into ws ----------------
    int row = (bid - PREP_FPS_END) * 2 + (t >> 7);
    int o = t & 127;
    if (row < 899) {
      float v; float* dst;
      if (row < 259)      { dst = wsf + WS_W0T + (size_t)row * 128; v = w0[(size_t)o * CIN + row]; }
      else if (row < 387) { int k = row - 259; dst = wsf + WS_W1T + (size_t)k * 128; v = w1[(size_t)o * 128 + k]; }
      else if (row < 515) { int k = row - 387; dst = wsf + WS_W2T + (size_t)k * 128; v = w2[(size_t)o * 128 + k]; }
      else if (row < 643) { int k = row - 515; dst = wsf + WS_C1T + (size_t)k * 128; v = c1w[(size_t)o * 128 + k]; }
      else if (row < 771) { int k = row - 643; dst = wsf + WS_C2T + (size_t)k * 128; v = c2w[(size_t)o * 128 + k]; }
      else                { int k = row - 771; dst = wsf + WS_C3T + (size_t)k * 128; v = (o < OUTCH) ? c3w[(size_t)o * 128 + k] : 0.f; }
      dst[o] = v;
    }
    return;
  }

  if (bid < PREP_SURF_END) {
    // ---------------- surface center selection ----------------
    int i = (bid - PREP_TR_END) * 256 + t;  // < 49152
    int src = i / (BB * KZZ);
    int rem = i % (BB * KZZ);
    int b = rem / KZZ, k = rem % KZZ;
    const float* ps = (src == 0) ? pz : ((src == 1) ? pxy : pl);
    const float* pc = (src == 0) ? cz : ((src == 1) ? cxy : cl);
    float x0 = ps[((size_t)b * 2 + 0) * KZZ + k];
    float x1 = ps[((size_t)b * 2 + 1) * KZZ + k];
    float add = (x1 <= x0) ? 10.0f : 0.0f;
    size_t dst;
    if (src == 0)      dst = O7 + ((size_t)b * 2048 + k) * 3;
    else if (src == 1) dst = O7 + ((size_t)b * 2048 + 1024 + k) * 3;
    else               dst = O9 + ((size_t)b * KZZ + k) * 3;
    const float* c3 = pc + ((size_t)b * KZZ + k) * 3;
    out[dst + 0] = c3[0] + add;
    out[dst + 1] = c3[1] + add;
    out[dst + 2] = c3[2] + add;
    return;
  }

  {
    // ---------------- aggregated feature concat copy ----------------
    int i = (bid - PREP_SURF_END) * 256 + t;  // < 1048576 float4s
    int q = i & 511;
    int bc = i >> 9;
    int half = q >> 8, k4 = q & 255;
    const float4* src = (const float4*)((half == 0) ? az : axy);
    float4 v = src[(size_t)bc * 256 + k4];
    float4* dst = (float4*)(out + O8);
    dst[(size_t)bc * 512 + q] = v;
  }
}

__global__ __launch_bounds__(256, 2) void proposal_kernel(
    const float* __restrict__ vote_xyz, const float* __restrict__ vote_feat,
    const float* __restrict__ wsf, const float* __restrict__ msa,
    const float* __restrict__ s0, const float* __restrict__ b0,
    const float* __restrict__ s1, const float* __restrict__ b1,
    const float* __restrict__ s2, const float* __restrict__ b2,
    const float* __restrict__ c1b, const float* __restrict__ bn1s, const float* __restrict__ bn1b,
    const float* __restrict__ c2b, const float* __restrict__ bn2s, const float* __restrict__ bn2b,
    const float* __restrict__ c3b,
    float* __restrict__ out) {
  __shared__ __align__(16) float Xs[4][CIN * 16];  // per-wave X / h ping-pong
  __shared__ int sel_s[4][NS];
  __shared__ float feat_s[4][CMLP];
  __shared__ float n1_s[4][CMLP], n2_s[4][CMLP], ntv_s[4][CMLP];
  __shared__ float sc_s[4][3], sh_s[4][3];
  __shared__ int scls_s[4];

  const int t = threadIdx.x;
  const int w = t >> 6, l = t & 63;
  const int b = blockIdx.x >> 6;
  const int pp = ((blockIdx.x & 63) << 2) + w;  // proposal id
  const int sh = l >> 5, og = l & 31;

  const float* nx = wsf + WS_NEWXYZ + ((size_t)b * NPROPN + pp) * 3;
  const float cx = nx[0], cy = nx[1], cz = nx[2];
  const float* px = vote_xyz + (size_t)b * KK * 3;
  const float RR = 0.09000000357627869f;  // f32(0.3f*0.3f)
  float* Xw = &Xs[w][0];

  // ---- ball query: first <=16 in-radius indices, ascending ----
  {
    int total = 0;
    for (int j = 0; j < 32; ++j) {
      int i = (j << 6) + l;
      float dx = __fsub_rn(px[i * 3 + 0], cx);
      float dy = __fsub_rn(px[i * 3 + 1], cy);
      float dz = __fsub_rn(px[i * 3 + 2], cz);
      float d = __fadd_rn(__fadd_rn(__fmul_rn(dx, dx), __fmul_rn(dy, dy)), __fmul_rn(dz, dz));
      bool in = (d <= RR);
      unsigned long long bal = __ballot(in);
      if (in) {
        int pos = total + __popcll(bal & ((1ull << l) - 1ull));
        if (pos < NS) sel_s[w][pos] = i;
      }
      total += __popcll(bal);
      if (total >= NS) break;
    }
    if (l == 0 && total < NS) {
      int first = (total > 0) ? sel_s[w][0] : 0;
      for (int i = total; i < NS; ++i) sel_s[w][i] = first;
    }
  }

  // ---- gather X[k][s] (swizzled) : k<3 = gx, k>=3 = features ----
  {
    const int s = l >> 2, q = l & 3;
    const int idx = sel_s[w][s];
    const int slo = s & 7, shi = s >> 3;
    if (q < 3) {
      float pv = px[idx * 3 + q];
      float cv = (q == 0) ? cx : ((q == 1) ? cy : cz);
      Xw[q * 16 + (((shi ^ (q & 1)) << 3)) + slo] = __fdiv_rn(__fsub_rn(pv, cv), 0.3f);
    }
    const float* fb = vote_feat + (size_t)b * CSEED * KK + idx;
    for (int m = 0; m < 64; ++m) {
      int c = (m << 2) + q;
      int k = c + 3;
      Xw[k * 16 + (((shi ^ (k & 1)) << 3)) + slo] = fb[(size_t)c * KK];
    }
  }

  // ---- 3 MLP layers, wave-private (no barriers: LDS is per-wave) ----
  float4 acc[8];
  auto zero_acc = [&]() {
#pragma unroll
    for (int i = 0; i < 8; ++i) acc[i] = make_float4(0.f, 0.f, 0.f, 0.f);
  };
  auto layer = [&](const float* __restrict__ WT, int K, int inRowBase) {
    for (int kk = 0; kk < K; ++kk) {
      int row = inRowBase + kk;
      const float* xr = Xw + row * 16 + ((sh ^ (row & 1)) << 3);
      float4 xa = *(const float4*)xr;
      float4 xb = *(const float4*)(xr + 4);
      float4 wv = *(const float4*)(WT + (size_t)kk * 128 + (og << 2));
      fma4(acc[0], xa.x, wv); fma4(acc[1], xa.y, wv);
      fma4(acc[2], xa.z, wv); fma4(acc[3], xa.w, wv);
      fma4(acc[4], xb.x, wv); fma4(acc[5], xb.y, wv);
      fma4(acc[6], xb.z, wv); fma4(acc[7], xb.w, wv);
    }
  };
  auto store_h = [&](const float* scv, const float* bbv, int outRowBase) {
    float4 sc = *(const float4*)(scv + (og << 2));
    float4 bb = *(const float4*)(bbv + (og << 2));
#pragma unroll
    for (int r = 0; r < 4; ++r) {
      float s_ = fget(sc, r), b_ = fget(bb, r);
      float q0 = fmaf(fget(acc[0], r), s_, b_); q0 = q0 > 0.f ? q0 : 0.f;
      float q1 = fmaf(fget(acc[1], r), s_, b_); q1 = q1 > 0.f ? q1 : 0.f;
      float q2 = fmaf(fget(acc[2], r), s_, b_); q2 = q2 > 0.f ? q2 : 0.f;
      float q3 = fmaf(fget(acc[3], r), s_, b_); q3 = q3 > 0.f ? q3 : 0.f;
      float q4 = fmaf(fget(acc[4], r), s_, b_); q4 = q4 > 0.f ? q4 : 0.f;
      float q5 = fmaf(fget(acc[5], r), s_, b_); q5 = q5 > 0.f ? q5 : 0.f;
      float q6 = fmaf(fget(acc[6], r), s_, b_); q6 = q6 > 0.f ? q6 : 0.f;
      float q7 = fmaf(fget(acc[7], r), s_, b_); q7 = q7 > 0.f ? q7 : 0.f;
      int row = outRowBase + (og << 2) + r;
      float* dst = Xw + row * 16 + ((sh ^ (row & 1)) << 3);
      *(float4*)dst = make_float4(q0, q1, q2, q3);
      *(float4*)(dst + 4) = make_float4(q4, q5, q6, q7);
    }
  };

  zero_acc();
  layer(wsf + WS_W0T, CIN, 0);
  store_h(s0, b0, 0);
  zero_acc();
  layer(wsf + WS_W1T, CMLP, 0);
  store_h(s1, b1, CMLP);
  zero_acc();
  layer(wsf + WS_W2T, CMLP, CMLP);

  // ---- epilogue L2 + maxpool over 16 samples ----
  float mr[4];
  {
    float4 sc = *(const float4*)(s2 + (og << 2));
    float4 bb = *(const float4*)(b2 + (og << 2));
#pragma unroll
    for (int r = 0; r < 4; ++r) {
      float s_ = fget(sc, r), b_ = fget(bb, r);
      float m = 0.f;  // relu outputs >= 0
#pragma unroll
      for (int i = 0; i < 8; ++i) {
        float v = fmaf(fget(acc[i], r), s_, b_);
        m = fmaxf(m, v);
      }
      float o2 = __shfl_xor(m, 32);
      mr[r] = fmaxf(m, o2);
    }
  }
  if (sh == 0) *(float4*)&feat_s[w][og << 2] = make_float4(mr[0], mr[1], mr[2], mr[3]);
  {
    float* o11 = out + O11 + (size_t)b * CMLP * 1536;
#pragma unroll
    for (int r = 0; r < 4; ++r) {
      size_t rowb = (size_t)((og << 2) + r) * 1536 + pp;
#pragma unroll
      for (int rr2 = 0; rr2 < 3; ++rr2) {
        int rr = sh * 3 + rr2;
        o11[rowb + rr * 256] = mr[r];
      }
    }
  }

  // ---- conv chain (per-wave; o = 2l, 2l+1) ----
  {
    const float* C1T = wsf + WS_C1T;
    float a0 = 0.f, a1 = 0.f;
    for (int k = 0; k < CMLP; ++k) {
      float f = feat_s[w][k];
      float2 wv = *(const float2*)(C1T + (size_t)k * 128 + (l << 1));
      a0 = fmaf(f, wv.x, a0); a1 = fmaf(f, wv.y, a1);
    }
    int o0 = l << 1, o1 = o0 + 1;
    float v0 = fmaf(a0 + c1b[o0], bn1s[o0], bn1b[o0]); v0 = v0 > 0.f ? v0 : 0.f;
    float v1 = fmaf(a1 + c1b[o1], bn1s[o1], bn1b[o1]); v1 = v1 > 0.f ? v1 : 0.f;
    *(float2*)&n1_s[w][o0] = make_float2(v0, v1);
  }
  {
    const float* C2T = wsf + WS_C2T;
    float a0 = 0.f, a1 = 0.f;
    for (int k = 0; k < CMLP; ++k) {
      float f = n1_s[w][k];
      float2 wv = *(const float2*)(C2T + (size_t)k * 128 + (l << 1));
      a0 = fmaf(f, wv.x, a0); a1 = fmaf(f, wv.y, a1);
    }
    int o0 = l << 1, o1 = o0 + 1;
    float v0 = fmaf(a0 + c2b[o0], bn2s[o0], bn2b[o0]); v0 = v0 > 0.f ? v0 : 0.f;
    float v1 = fmaf(a1 + c2b[o1], bn2s[o1], bn2b[o1]); v1 = v1 > 0.f ? v1 : 0.f;
    *(float2*)&n2_s[w][o0] = make_float2(v0, v1);
  }
  {
    const float* C3T = wsf + WS_C3T;
    float a0 = 0.f, a1 = 0.f;
    for (int k = 0; k < CMLP; ++k) {
      float f = n2_s[w][k];
      float2 wv = *(const float2*)(C3T + (size_t)k * 128 + (l << 1));
      a0 = fmaf(f, wv.x, a0); a1 = fmaf(f, wv.y, a1);
    }
    int o0 = l << 1, o1 = o0 + 1;
    float bb0 = (o0 < OUTCH) ? c3b[o0] : 0.f;
    float bb1 = (o1 < OUTCH) ? c3b[o1] : 0.f;
    *(float2*)&ntv_s[w][o0] = make_float2(a0 + bb0, a1 + bb1);
  }

  // ---- heads (wave-private) ----
  {
    const float* ntv = &ntv_s[w][0];
    const size_t bp = (size_t)b * NPROPN + pp;
    if (l < 2) out[O0 + bp * 2 + l] = ntv[l];
    if (l < 3) {
      float cv = ((l == 0) ? cx : ((l == 1) ? cy : cz)) + ntv[2 + l];
      sc_s[w][l] = cv;
      out[O1 + bp * 3 + l] = cv;
    }
    if (l < 12) {
      out[O2 + bp * 12 + l] = ntv[5 + l];
      out[O3 + bp * 12 + l] = ntv[17 + l] * 0.2617993877991494f;
    }
    if (l < 18) {
      out[O4 + bp * 18 + l] = ntv[29 + l];
      out[O6 + bp * 18 + l] = ntv[101 + l];
    }
    if (l < 54) out[O5 + bp * 54 + l] = ntv[47 + l] * msa[l];
    if (l == 0) {
      float bvv = ntv[29]; int bii = 0;
      for (int i2 = 1; i2 < 18; ++i2)
        if (ntv[29 + i2] > bvv) { bvv = ntv[29 + i2]; bii = i2; }
      scls_s[w] = bii;
    }
    if (l < 3) {
      int cls = scls_s[w];
      float m = msa[cls * 3 + l];
      sh_s[w][l] = fmaf(ntv[47 + cls * 3 + l], m, m) * 0.5f;
    }
    if (l < 18) {
      const int r = l / 3, j2 = l % 3;
      const int axis[6] = {2, 2, 1, 1, 0, 0};
      float v = sc_s[w][j2];
      if (j2 == axis[r]) v = (r & 1) ? (v - sh_s[w][j2]) : (v + sh_s[w][j2]);
      out[O10 + (size_t)b * 4608 + (size_t)(r * 256 + pp) * 3 + j2] = v;
    }
  }
}

extern "C" void kernel_launch(void* const* d_in, const int* in_sizes, int n_in,
                              void* d_out, int out_size, void* d_ws, size_t ws_size,
                              hipStream_t stream) {
  (void)in_sizes; (void)n_in; (void)out_size; (void)ws_size;
  const float* vote_xyz = (const float*)d_in[0];
  const float* vote_feat = (const float*)d_in[1];
  const float* pz   = (const float*)d_in[2];
  const float* cz   = (const float*)d_in[3];
  const float* az   = (const float*)d_in[4];
  const float* pxy  = (const float*)d_in[5];
  const float* cxy  = (const float*)d_in[6];
  const float* axy  = (const float*)d_in[7];
  const float* pl   = (const float*)d_in[8];
  const float* cl   = (const float*)d_in[9];
  const float* msa  = (const float*)d_in[11];
  const float* w0   = (const float*)d_in[12];
  const float* s0   = (const float*)d_in[13];
  const float* b0   = (const float*)d_in[14];
  const float* w1   = (const float*)d_in[15];
  const float* s1   = (const float*)d_in[16];
  const float* b1   = (const float*)d_in[17];
  const float* w2   = (const float*)d_in[18];
  const float* s2   = (const float*)d_in[19];
  const float* b2   = (const float*)d_in[20];
  const float* c1w  = (const float*)d_in[21];
  const float* c1b  = (const float*)d_in[22];
  const float* bn1s = (const float*)d_in[23];
  const float* bn1b = (const float*)d_in[24];
  const float* c2w  = (const float*)d_in[25];
  const float* c2b  = (const float*)d_in[26];
  const float* bn2s = (const float*)d_in[27];
  const float* bn2b = (const float*)d_in[28];
  const float* c3w  = (const float*)d_in[29];
  const float* c3b  = (const float*)d_in[30];
  float* out = (float*)d_out;
  float* wsf = (float*)d_ws;

  hipLaunchKernelGGL(prep_kernel, dim3(PREP_COPY_END), dim3(256), 0, stream,
                     vote_xyz, w0, w1, w2, c1w, c2w, c3w,
                     pz, cz, pxy, cxy, pl, cl, az, axy, wsf, out);
  hipLaunchKernelGGL(proposal_kernel, dim3(BB * NPROPN / 4), dim3(256), 0, stream,
                     vote_xyz, vote_feat, wsf, msa,
                     s0, b0, s1, b1, s2, b2,
                     c1b, bn1s, bn1b, c2b, bn2s, bn2b, c3b, out);
}